// Round 17
// baseline (163.458 us; speedup 1.0000x reference)
//
#include <hip/hip_runtime.h>
#include <math.h>

// Problem: B=16, LQ=1024, LK=1024, DK=256, DV=256, fp32 in/out, mask int32.
// Identity: softmax_k(q_s + k_s with mask) == mask-weighted softmax of k_s alone
// (q_s cancels; masked entries are exactly -1e9 -> weight 0). query never read.
// k_s ~ N(0,256) => softmax mass concentrates in top ~30-60 keys; chunk-0
// (top-64) provably terminates ~all rows (e_64 ~ e^-26 * Z << 1e-5 * Z).
//
// R1-R16 summary: best core = {ksm streamer: ks dot + mask->2MB bit table} ->
// {attn: local per-block select + LDS-staged top-V walk, 4 rows/wave, weights
// scalar-selected from SGPR ballot masks}. R16 = 158.0us, all kernels below
// the 40us harness fills. Residual flaw: 74KB LDS x 512 blocks = exactly 2
// blocks/CU, zero queued -> no cross-block phase overlap.
// R17: NSTAGE 64->32 (LDS ~42KB -> 3 blocks/CU resident) + 256-thr/16-row
// blocks, grid 1024 (4 blocks scheduled per CU) -> select/stage memory
// phases of one block overlap walk/epilogue of another. Walk entries 32-63
// (negligible mass, needed for exactness) read V via uniform L2-hot loads.

#define NB     16
#define NL     1024     // LQ == LK
#define ND     256      // DK == DV
#define NBKT   128      // buckets of width 1.0 in log-space
#define NSTAGE 32       // V rows staged in LDS (entries 0..31 of chunk 0)

// ---- Kernel A: ks[b,k] = dot(key[b,k,:], w)  +  mask-row bit compression ----
// 4 waves/block, 1 row/wave, grid 4096. Pure streamer: key 16.7MB + mask
// 64MB coalesced reads, 2MB bit-table + 64KB ks writes. No LDS, no barriers.
__global__ __launch_bounds__(256)
void ksm_kernel(const float* __restrict__ key, const float* __restrict__ w,
                const int* __restrict__ mask,
                float* __restrict__ ks, unsigned short* __restrict__ bmtab) {
    int wid  = threadIdx.x >> 6;
    int lane = threadIdx.x & 63;
    int row  = blockIdx.x * 4 + wid;               // 0 .. NB*NL-1

    // independent loads, all issued up front
    const float4* krow = (const float4*)(key + (size_t)row * ND);
    float4 kv = krow[lane];
    float4 wv = ((const float4*)w)[lane];
    const int4* mrow4 = (const int4*)(mask + (size_t)row * NL);
    int4 m0 = mrow4[lane], m1 = mrow4[lane + 64];
    int4 m2 = mrow4[lane + 128], m3 = mrow4[lane + 192];

    // key dot -> wave reduce
    float p = kv.x * wv.x + kv.y * wv.y + kv.z * wv.z + kv.w * wv.w;
    #pragma unroll
    for (int off = 32; off > 0; off >>= 1)
        p += __shfl_xor(p, off, 64);

    // mask bits: bit (4j + c) of lane L's word = (mask[row][256j+4L+c] != 0)
    unsigned int bits = 0;
    bits |= (m0.x != 0 ? 1u : 0u) << 0;  bits |= (m0.y != 0 ? 1u : 0u) << 1;
    bits |= (m0.z != 0 ? 1u : 0u) << 2;  bits |= (m0.w != 0 ? 1u : 0u) << 3;
    bits |= (m1.x != 0 ? 1u : 0u) << 4;  bits |= (m1.y != 0 ? 1u : 0u) << 5;
    bits |= (m1.z != 0 ? 1u : 0u) << 6;  bits |= (m1.w != 0 ? 1u : 0u) << 7;
    bits |= (m2.x != 0 ? 1u : 0u) << 8;  bits |= (m2.y != 0 ? 1u : 0u) << 9;
    bits |= (m2.z != 0 ? 1u : 0u) << 10; bits |= (m2.w != 0 ? 1u : 0u) << 11;
    bits |= (m3.x != 0 ? 1u : 0u) << 12; bits |= (m3.y != 0 ? 1u : 0u) << 13;
    bits |= (m3.z != 0 ? 1u : 0u) << 14; bits |= (m3.w != 0 ? 1u : 0u) << 15;

    bmtab[(size_t)row * 64 + lane] = (unsigned short)bits;   // 128B/row coalesced
    if (lane == 0) ks[row] = p;
}

// ---------------- Kernel B: fused select + attention ----------------
// 256 threads = 4 waves; block = 16 rows of one batch; grid 1024; LDS ~42KB
// -> 3 blocks/CU resident, 4 scheduled -> cross-block phase overlap.
// Phase 1 (local select): batch ks (4KB, L2-hot) -> block max, e=exp,
//   counting-sort into LDS pk_lds, per-chunk sums csum[16]. Any per-block
//   order with exact suffix masses is correct (R1 argument).
// Phase 2 (walk): top-NSTAGE V rows in LDS; ONE WAVE = 4 ROWS; mask bits
//   from the bit table (4x 2B gathers); fixed-64 walk: i<NSTAGE from LDS,
//   i>=NSTAGE via wave-uniform L2-hot loads; weights scalar-selected.
__global__ __launch_bounds__(256)
void attn_kernel(const float* __restrict__ value, const int* __restrict__ mask,
                 const float* __restrict__ ks,
                 const unsigned short* __restrict__ bmtab,
                 float* __restrict__ out) {
    __shared__ float  lds_V[NSTAGE * ND];   // 32 KB: top-NSTAGE value rows
    __shared__ float2 pk_lds[NL];           // 8 KB: (e, idx) bucket-desc order
    __shared__ int    cnt[NBKT];            // histogram
    __shared__ int    cur[NBKT];            // scan -> scatter cursors
    __shared__ float  wred[4];              // per-wave max
    __shared__ float  csum[16];             // per-chunk sums

    const int t    = threadIdx.x;           // 0..255
    const int wid  = t >> 6;                // 0..3
    const int lane = t & 63;
    const int row0 = blockIdx.x * 16 + wid * 4;   // wave's 4 rows
    const int b    = row0 >> 10;

    const float4* vbase = (const float4*)(value + ((size_t)b << 10) * ND);
    const float*  ksb   = ks + b * NL;

    // ================= phase 1: local select =================
    if (t < NBKT) cnt[t] = 0;

    // 4 entries per thread, coalesced (stride 256)
    float v0 = ksb[t], v1 = ksb[t + 256], v2 = ksb[t + 512], v3 = ksb[t + 768];

    // block max: thread max4 -> wave shuffle reduce -> 4-way LDS combine
    float mx = fmaxf(fmaxf(v0, v1), fmaxf(v2, v3));
    #pragma unroll
    for (int off = 32; off > 0; off >>= 1)
        mx = fmaxf(mx, __shfl_xor(mx, off, 64));
    if (lane == 0) wred[wid] = mx;
    __syncthreads();                                        // #1 (covers cnt=0)
    const float m = fmaxf(fmaxf(wred[0], wred[1]), fmaxf(wred[2], wred[3]));

    float e0v = __expf(v0 - m), e1v = __expf(v1 - m);
    float e2v = __expf(v2 - m), e3v = __expf(v3 - m);
    int b0 = (int)fminf(m - v0, (float)(NBKT - 1));         // m - v >= 0
    int b1 = (int)fminf(m - v1, (float)(NBKT - 1));
    int b2 = (int)fminf(m - v2, (float)(NBKT - 1));
    int b3 = (int)fminf(m - v3, (float)(NBKT - 1));
    atomicAdd(&cnt[b0], 1); atomicAdd(&cnt[b1], 1);
    atomicAdd(&cnt[b2], 1); atomicAdd(&cnt[b3], 1);
    __syncthreads();                                        // #2

    // exclusive scan of cnt[128] by wave 0 via shuffles
    if (wid == 0) {
        int a   = cnt[lane];
        int b2v = cnt[lane + 64];
        int sa = a, sb = b2v;
        #pragma unroll
        for (int d = 1; d < 64; d <<= 1) {
            int na = __shfl_up(sa, d, 64);
            int nb = __shfl_up(sb, d, 64);
            if (lane >= d) { sa += na; sb += nb; }
        }
        int tot = __shfl(sa, 63, 64);
        sb += tot;
        cur[lane]      = sa - a;
        cur[lane + 64] = sb - b2v;
    }
    __syncthreads();                                        // #3

    // scatter (bijective within the block)
    int p0i = atomicAdd(&cur[b0], 1);
    int p1i = atomicAdd(&cur[b1], 1);
    int p2i = atomicAdd(&cur[b2], 1);
    int p3i = atomicAdd(&cur[b3], 1);
    pk_lds[p0i] = make_float2(e0v, __int_as_float(t));
    pk_lds[p1i] = make_float2(e1v, __int_as_float(t + 256));
    pk_lds[p2i] = make_float2(e2v, __int_as_float(t + 512));
    pk_lds[p3i] = make_float2(e3v, __int_as_float(t + 768));
    __syncthreads();                                        // #4 (pk_lds ready)

    // per-chunk sums: wave w reduces chunks 4w..4w+3
    #pragma unroll
    for (int cc = 0; cc < 4; ++cc) {
        int chunk = wid * 4 + cc;
        float s = pk_lds[chunk * 64 + lane].x;
        #pragma unroll
        for (int off = 32; off > 0; off >>= 1)
            s += __shfl_xor(s, off, 64);
        if (lane == 0) csum[chunk] = s;
    }

    // ================= phase 2: walk prep =================
    // top-64 metadata, lane-parallel (shared by all rows of the batch)
    float2 p0 = pk_lds[lane];
    int   k0  = __float_as_int(p0.y);
    float e0  = p0.x;
    int   e0i = __float_as_int(e0);

    // bit for column k0 lives in word (k0>>2)&63, bit (k0&3)+4*(k0>>8)
    const int L     = (k0 >> 2) & 63;
    const int shift = (k0 & 3) + ((k0 >> 8) << 2);

    // 4 independent 2B gathers (128B/row table rows, L2/L3-hot)
    unsigned short t0 = bmtab[(size_t)(row0 + 0) * 64 + L];
    unsigned short t1 = bmtab[(size_t)(row0 + 1) * 64 + L];
    unsigned short t2 = bmtab[(size_t)(row0 + 2) * 64 + L];
    unsigned short t3 = bmtab[(size_t)(row0 + 3) * 64 + L];

    // stage top-NSTAGE V rows: wave w stages slots 8w..8w+7 (coalesced 1KB)
    #pragma unroll
    for (int j = 0; j < 8; ++j) {
        int s   = wid * 8 + j;                          // 0..31
        int ksr = __builtin_amdgcn_readlane(k0, s);     // uniform -> SGPR base
        ((float4*)lds_V)[s * 64 + lane] = vbase[(size_t)ksr * 64 + lane];
    }

    bool mb0 = (t0 >> shift) & 1;
    bool mb1 = (t1 >> shift) & 1;
    bool mb2 = (t2 >> shift) & 1;
    bool mb3 = (t3 >> shift) & 1;
    unsigned long long bm0 = __ballot(mb0);
    unsigned long long bm1 = __ballot(mb1);
    unsigned long long bm2 = __ballot(mb2);
    unsigned long long bm3 = __ballot(mb3);

    // Z per row: butterfly of mask-selected e (uniform result)
    auto zsum = [&](bool mb) -> float {
        float wz = mb ? e0 : 0.0f;
        #pragma unroll
        for (int off = 32; off > 0; off >>= 1)
            wz += __shfl_xor(wz, off, 64);
        return wz;
    };
    float z0 = zsum(mb0), z1 = zsum(mb1), z2 = zsum(mb2), z3 = zsum(mb3);

    __syncthreads();   // #5: lds_V + csum ready

    // ---- walk: fixed 64 iterations; i<NSTAGE from LDS, rest uniform L2 ----
    float4 acc0 = make_float4(0.f, 0.f, 0.f, 0.f);
    float4 acc1 = make_float4(0.f, 0.f, 0.f, 0.f);
    float4 acc2 = make_float4(0.f, 0.f, 0.f, 0.f);
    float4 acc3 = make_float4(0.f, 0.f, 0.f, 0.f);

    #pragma unroll 16
    for (int i = 0; i < NSTAGE; ++i) {
        float4 v = ((const float4*)lds_V)[i * 64 + lane];
        float ei = __int_as_float(__builtin_amdgcn_readlane(e0i, i));
        float w0 = ((bm0 >> i) & 1ull) ? ei : 0.0f;      // s_cselect
        float w1 = ((bm1 >> i) & 1ull) ? ei : 0.0f;
        float w2 = ((bm2 >> i) & 1ull) ? ei : 0.0f;
        float w3 = ((bm3 >> i) & 1ull) ? ei : 0.0f;
        acc0.x += w0 * v.x; acc0.y += w0 * v.y; acc0.z += w0 * v.z; acc0.w += w0 * v.w;
        acc1.x += w1 * v.x; acc1.y += w1 * v.y; acc1.z += w1 * v.z; acc1.w += w1 * v.w;
        acc2.x += w2 * v.x; acc2.y += w2 * v.y; acc2.z += w2 * v.z; acc2.w += w2 * v.w;
        acc3.x += w3 * v.x; acc3.y += w3 * v.y; acc3.z += w3 * v.z; acc3.w += w3 * v.w;
    }
    #pragma unroll 8
    for (int i = NSTAGE; i < 64; ++i) {
        int ksr  = __builtin_amdgcn_readlane(k0, i);     // uniform -> SGPR base
        float4 v = vbase[(size_t)ksr * 64 + lane];       // coalesced 1KB, L2-hot
        float ei = __int_as_float(__builtin_amdgcn_readlane(e0i, i));
        float w0 = ((bm0 >> i) & 1ull) ? ei : 0.0f;
        float w1 = ((bm1 >> i) & 1ull) ? ei : 0.0f;
        float w2 = ((bm2 >> i) & 1ull) ? ei : 0.0f;
        float w3 = ((bm3 >> i) & 1ull) ? ei : 0.0f;
        acc0.x += w0 * v.x; acc0.y += w0 * v.y; acc0.z += w0 * v.z; acc0.w += w0 * v.w;
        acc1.x += w1 * v.x; acc1.y += w1 * v.y; acc1.z += w1 * v.z; acc1.w += w1 * v.w;
        acc2.x += w2 * v.x; acc2.y += w2 * v.y; acc2.z += w2 * v.z; acc2.w += w2 * v.w;
        acc3.x += w3 * v.x; acc3.y += w3 * v.y; acc3.z += w3 * v.z; acc3.w += w3 * v.w;
    }

    // suffix mass after chunk 0 = sum csum[1..15] (LDS reads, no reg array)
    float remA = 0.0f;
    #pragma unroll
    for (int j = 1; j < 16; ++j) remA += csum[j];

    // ---- per-row epilogue: done check, rare deep chunks, store ----
    auto finish_row = [&](int r, float4 acc, float Z) {
        const int* mrow = mask + (size_t)(row0 + r) * NL;
        float rsuf = remA;
        bool done = (rsuf <= 1e-5f * Z);     // Z==0 -> rem>0 -> continue
        for (int c = 1; c < 16 && !done; ++c) {           // ~never taken
            float2 p = pk_lds[c * 64 + lane];
            float e  = p.x;
            int   k  = __float_as_int(p.y);
            bool mb  = (mrow[k] != 0);
            float dz = mb ? e : 0.0f;
            #pragma unroll
            for (int off = 32; off > 0; off >>= 1)
                dz += __shfl_xor(dz, off, 64);
            unsigned long long bmx = __ballot(mb);
            int eI = __float_as_int(e);
            for (int i = 0; i < 64; ++i) {                // rolled: rare path
                float ei = __int_as_float(__builtin_amdgcn_readlane(eI, i));
                int   ki = __builtin_amdgcn_readlane(k, i);
                float w  = ((bmx >> i) & 1ull) ? ei : 0.0f;
                float4 v = vbase[(size_t)ki * 64 + lane];
                acc.x += w * v.x; acc.y += w * v.y;
                acc.z += w * v.z; acc.w += w * v.w;
            }
            Z += dz;
            rsuf -= csum[c];
            done = (rsuf <= 1e-5f * Z);
        }
        float4* orow = (float4*)(out + (size_t)(row0 + r) * ND);
        if (Z > 0.0f) {
            float inv = 1.0f / Z;
            orow[lane] = make_float4(acc.x * inv, acc.y * inv,
                                     acc.z * inv, acc.w * inv);
        } else {
            // all-masked row: softmax over constant -1e9 -> uniform average
            float4 s = make_float4(0.f, 0.f, 0.f, 0.f);
            for (int k = 0; k < NL; ++k) {
                float4 v = vbase[(size_t)k * 64 + lane];
                s.x += v.x; s.y += v.y; s.z += v.z; s.w += v.w;
            }
            const float inv = 1.0f / (float)NL;
            orow[lane] = make_float4(s.x * inv, s.y * inv, s.z * inv, s.w * inv);
        }
    };
    finish_row(0, acc0, z0);
    finish_row(1, acc1, z1);
    finish_row(2, acc2, z2);
    finish_row(3, acc3, z3);
}

extern "C" void kernel_launch(void* const* d_in, const int* in_sizes, int n_in,
                              void* d_out, int out_size, void* d_ws, size_t ws_size,
                              hipStream_t stream) {
    // setup_inputs order: query, key, value, w, mask   (query unused!)
    const float* key   = (const float*)d_in[1];
    const float* value = (const float*)d_in[2];
    const float* w     = (const float*)d_in[3];
    const int*   mask  = (const int*)d_in[4];
    float*       outp  = (float*)d_out;

    float* ks = (float*)d_ws;                    // 16*1024 f32
    unsigned short* bmtab =
        (unsigned short*)(ks + NB * NL);         // 16*1024 x 64 u16 bit table (2MB)

    ksm_kernel <<<NB * NL / 4, 256, 0, stream>>>(key, w, mask, ks, bmtab);
    attn_kernel<<<NB * NL / 16, 256, 0, stream>>>(value, mask, ks, bmtab, outp);
}